// Round 3
// baseline (474.564 us; speedup 1.0000x reference)
//
#include <hip/hip_runtime.h>
#include <hip/hip_bf16.h>
#include <stdint.h>

// ---------------- problem constants ----------------
#define N_NODES 16384
#define D_IN    256
#define D_OUT   256
#define K_SAMP  10
#define HALF_FLAT (1u << 27)

// JAX PRNG mode: 1 = jax_threefry_partitionable (modern default), 0 = legacy split-iota
#define JAX_PARTITIONABLE 1

__device__ __forceinline__ uint32_t rotl32(uint32_t x, int r) {
    return (x << r) | (x >> (32 - r));
}

// Exact replica of jax threefry2x32 noise bits for flat index i = r*16384 + c, key (0,42).
__device__ __forceinline__ uint32_t jax_noise_bits(uint32_t r, uint32_t c) {
    const uint32_t i  = (r << 14) | c;
    const uint32_t k0 = 0u, k1 = 42u;
    const uint32_t k2 = 42u ^ 0x1BD11BDAu;
    uint32_t x0, x1;
#if JAX_PARTITIONABLE
    x0 = 0u;            // hi32 of uint64 flat counter
    x1 = i;             // lo32
#else
    const bool lo = (i < HALF_FLAT);
    x0 = lo ? i : (i - HALF_FLAT);
    x1 = lo ? (i + HALF_FLAT) : i;
#endif
    x0 += k0; x1 += k1;
#define TFR4(a,b,cc,d) \
    x0 += x1; x1 = rotl32(x1,a);  x1 ^= x0; \
    x0 += x1; x1 = rotl32(x1,b);  x1 ^= x0; \
    x0 += x1; x1 = rotl32(x1,cc); x1 ^= x0; \
    x0 += x1; x1 = rotl32(x1,d);  x1 ^= x0;
    TFR4(13,15,26,6);   x0 += k1; x1 += k2 + 1u;
    TFR4(17,29,16,24);  x0 += k2; x1 += k0 + 2u;
    TFR4(13,15,26,6);   x0 += k0; x1 += k1 + 3u;
    TFR4(17,29,16,24);  x0 += k1; x1 += k2 + 4u;
    TFR4(13,15,26,6);   x0 += k2; x1 += k0 + 5u;
#undef TFR4
#if JAX_PARTITIONABLE
    return x0 ^ x1;
#else
    return (i < HALF_FLAT) ? x0 : x1;
#endif
}

// ---------------- kernel 1: sample + mean-aggregate → agg (f32) into d_out ----------------
// one block (256 threads) per node. d_out temporarily holds agg[N][256] f32.
__global__ __launch_bounds__(256) void k_agg(
    const float* __restrict__ x, const float* __restrict__ adj,
    float* __restrict__ aggout)
{
    const int r = blockIdx.x;
    const int t = threadIdx.x;

    __shared__ unsigned long long cand[512];
    __shared__ int ncand;
    __shared__ int bcol;

    if (t == 0) ncand = 0;
    __syncthreads();

    const float4* rowp = (const float4*)(adj + (size_t)r * N_NODES);
    for (int it = 0; it < N_NODES / 1024; ++it) {          // 16 iters
        float4 v = rowp[it * 256 + t];
        int cb = (it * 256 + t) * 4;
        float vv[4] = {v.x, v.y, v.z, v.w};
        #pragma unroll
        for (int j = 0; j < 4; ++j) {
            if (vv[j] != 0.0f) {
                uint32_t c   = (uint32_t)(cb + j);
                uint32_t u23 = jax_noise_bits((uint32_t)r, c) >> 9;   // monotone with uniform
                // key: larger noise wins; tie -> smaller col. +1 so key > 0 always.
                unsigned long long key =
                    ((((unsigned long long)u23) << 14) | (unsigned long long)(16383u - c)) + 1ull;
                int slot = atomicAdd(&ncand, 1);
                if (slot < 512) cand[slot] = key;
            }
        }
    }
    __syncthreads();

    int nc = ncand; if (nc > 512) nc = 512;
    const int m = nc < K_SAMP ? nc : K_SAMP;

    float acc = 0.0f;
    for (int s = 0; s < m; ++s) {
        if (t < 64) {                                      // wave 0 picks the max
            unsigned long long best = 0ull;
            for (int q = t; q < nc; q += 64) {
                unsigned long long comb = (cand[q] << 10) | (unsigned long long)(q + 1);
                if (comb > best) best = comb;
            }
            #pragma unroll
            for (int o = 1; o < 64; o <<= 1) {
                unsigned long long other = __shfl_xor(best, o);
                if (other > best) best = other;
            }
            if (t == 0) {
                int slot = (int)(best & 0x3FFull) - 1;
                unsigned long long key = (best >> 10) - 1ull;   // undo +1
                cand[slot] = 0ull;                              // remove winner
                bcol = 16383 - (int)(key & 0x3FFFull);          // recover column
            }
        }
        __syncthreads();
        acc += x[(size_t)bcol * D_IN + t];                      // coalesced gather
        __syncthreads();                                        // protect bcol/cand ordering
    }

    const float aggv = (m > 0) ? acc * (1.0f / (float)m) : 0.0f;
    aggout[(size_t)r * D_IN + t] = aggv;
}

// ---------------- kernel 2: in-place out = relu([x|agg] @ W^T + b), f32 VALU ----------------
// Block owns GM=32 rows. Stages x + its own agg rows (from d_out) into LDS BEFORE any
// store (block-private in-place, race-free). W streamed from global (512 KB, L2-resident).
#define GM 32

__global__ __launch_bounds__(256) void k_out(
    const float* __restrict__ x, const float* __restrict__ W,
    const float* __restrict__ bias, float* __restrict__ out)
{
    __shared__ float hl[GM][512];   // exactly 64 KB

    const int t  = threadIdx.x;
    const int m0 = blockIdx.x * GM;

    // stage x -> hl[:, 0:256]
    for (int q = t; q < GM * 64; q += 256) {
        int row = q >> 6, c4 = q & 63;
        float4 v = *(const float4*)(x + (size_t)(m0 + row) * D_IN + c4 * 4);
        *(float4*)&hl[row][c4 * 4] = v;
    }
    // stage agg (current contents of out) -> hl[:, 256:512]
    for (int q = t; q < GM * 64; q += 256) {
        int row = q >> 6, c4 = q & 63;
        float4 v = *(const float4*)(out + (size_t)(m0 + row) * D_OUT + c4 * 4);
        *(float4*)&hl[row][256 + c4 * 4] = v;
    }
    __syncthreads();

    const int c = t & 31;      // col within 32-col chunk
    const int g = t >> 5;      // row group: rows g*4 .. g*4+3

    #pragma unroll 1
    for (int ch = 0; ch < 8; ++ch) {
        const int n = ch * 32 + c;
        const float* wrow = W + (size_t)n * (2 * D_IN);
        float a0 = 0.f, a1 = 0.f, a2 = 0.f, a3 = 0.f;
        #pragma unroll 4
        for (int k4 = 0; k4 < 512; k4 += 4) {
            float4 w  = *(const float4*)(wrow + k4);
            float4 h0 = *(const float4*)&hl[g * 4 + 0][k4];
            float4 h1 = *(const float4*)&hl[g * 4 + 1][k4];
            float4 h2 = *(const float4*)&hl[g * 4 + 2][k4];
            float4 h3 = *(const float4*)&hl[g * 4 + 3][k4];
            a0 += h0.x * w.x + h0.y * w.y + h0.z * w.z + h0.w * w.w;
            a1 += h1.x * w.x + h1.y * w.y + h1.z * w.z + h1.w * w.w;
            a2 += h2.x * w.x + h2.y * w.y + h2.z * w.z + h2.w * w.w;
            a3 += h3.x * w.x + h3.y * w.y + h3.z * w.z + h3.w * w.w;
        }
        const float bv = bias[n];
        float r0 = a0 + bv, r1 = a1 + bv, r2 = a2 + bv, r3 = a3 + bv;
        out[(size_t)(m0 + g * 4 + 0) * D_OUT + n] = r0 > 0.f ? r0 : 0.f;
        out[(size_t)(m0 + g * 4 + 1) * D_OUT + n] = r1 > 0.f ? r1 : 0.f;
        out[(size_t)(m0 + g * 4 + 2) * D_OUT + n] = r2 > 0.f ? r2 : 0.f;
        out[(size_t)(m0 + g * 4 + 3) * D_OUT + n] = r3 > 0.f ? r3 : 0.f;
    }
}

// ---------------- launch ----------------
extern "C" void kernel_launch(void* const* d_in, const int* in_sizes, int n_in,
                              void* d_out, int out_size, void* d_ws, size_t ws_size,
                              hipStream_t stream) {
    (void)in_sizes; (void)n_in; (void)d_ws; (void)ws_size; (void)out_size;
    const float* x   = (const float*)d_in[0];
    const float* adj = (const float*)d_in[1];
    const float* W   = (const float*)d_in[2];
    const float* b   = (const float*)d_in[3];
    float* out = (float*)d_out;

    hipLaunchKernelGGL(k_agg, dim3(N_NODES), dim3(256), 0, stream, x, adj, out);
    hipLaunchKernelGGL(k_out, dim3(N_NODES / GM), dim3(256), 0, stream, x, W, b, out);
}

// Round 4
// 261.373 us; speedup vs baseline: 1.8157x; 1.8157x over previous
//
#include <hip/hip_runtime.h>
#include <hip/hip_bf16.h>
#include <stdint.h>

// ---------------- problem constants ----------------
#define N_NODES 16384
#define D_IN    256
#define D_OUT   256
#define K_SAMP  10
#define HALF_FLAT (1u << 27)

// JAX PRNG mode: 1 = jax_threefry_partitionable (modern default) — verified correct in R3.
#define JAX_PARTITIONABLE 1

__device__ __forceinline__ uint32_t rotl32(uint32_t x, int r) {
    return (x << r) | (x >> (32 - r));
}

// Exact replica of jax threefry2x32 noise bits for flat index i = r*16384 + c, key (0,42).
__device__ __forceinline__ uint32_t jax_noise_bits(uint32_t r, uint32_t c) {
    const uint32_t i  = (r << 14) | c;
    const uint32_t k0 = 0u, k1 = 42u;
    const uint32_t k2 = 42u ^ 0x1BD11BDAu;
    uint32_t x0, x1;
#if JAX_PARTITIONABLE
    x0 = 0u;
    x1 = i;
#else
    const bool lo = (i < HALF_FLAT);
    x0 = lo ? i : (i - HALF_FLAT);
    x1 = lo ? (i + HALF_FLAT) : i;
#endif
    x0 += k0; x1 += k1;
#define TFR4(a,b,cc,d) \
    x0 += x1; x1 = rotl32(x1,a);  x1 ^= x0; \
    x0 += x1; x1 = rotl32(x1,b);  x1 ^= x0; \
    x0 += x1; x1 = rotl32(x1,cc); x1 ^= x0; \
    x0 += x1; x1 = rotl32(x1,d);  x1 ^= x0;
    TFR4(13,15,26,6);   x0 += k1; x1 += k2 + 1u;
    TFR4(17,29,16,24);  x0 += k2; x1 += k0 + 2u;
    TFR4(13,15,26,6);   x0 += k0; x1 += k1 + 3u;
    TFR4(17,29,16,24);  x0 += k1; x1 += k2 + 4u;
    TFR4(13,15,26,6);   x0 += k2; x1 += k0 + 5u;
#undef TFR4
#if JAX_PARTITIONABLE
    return x0 ^ x1;
#else
    return (i < HALF_FLAT) ? x0 : x1;
#endif
}

__device__ __forceinline__ unsigned short f2bfbits(float f) {
    __hip_bfloat16 h = __float2bfloat16(f);
    return *(unsigned short*)&h;
}

// ---------------- kernel 1: sample + mean-aggregate → h = [x | agg] bf16 in ws ----------
// one block (256 threads) per node.
__global__ __launch_bounds__(256) void k_agg(
    const float* __restrict__ x, const float* __restrict__ adj,
    unsigned short* __restrict__ h)
{
    const int r = blockIdx.x;
    const int t = threadIdx.x;

    __shared__ unsigned long long cand[512];
    __shared__ int ncand;
    __shared__ int bcol;

    if (t == 0) ncand = 0;
    __syncthreads();

    const float4* rowp = (const float4*)(adj + (size_t)r * N_NODES);
    for (int it = 0; it < N_NODES / 1024; ++it) {          // 16 iters, 64KB row stream
        float4 v = rowp[it * 256 + t];
        int cb = (it * 256 + t) * 4;
        float vv[4] = {v.x, v.y, v.z, v.w};
        #pragma unroll
        for (int j = 0; j < 4; ++j) {
            if (vv[j] != 0.0f) {
                uint32_t c   = (uint32_t)(cb + j);
                uint32_t u23 = jax_noise_bits((uint32_t)r, c) >> 9;   // monotone with uniform
                // key: larger noise wins; tie -> smaller col. +1 so key > 0 always.
                unsigned long long key =
                    ((((unsigned long long)u23) << 14) | (unsigned long long)(16383u - c)) + 1ull;
                int slot = atomicAdd(&ncand, 1);
                if (slot < 512) cand[slot] = key;
            }
        }
    }
    __syncthreads();

    int nc = ncand; if (nc > 512) nc = 512;
    const int m = nc < K_SAMP ? nc : K_SAMP;

    float acc = 0.0f;
    for (int s = 0; s < m; ++s) {
        if (t < 64) {                                      // wave 0 picks the max
            unsigned long long best = 0ull;
            for (int q = t; q < nc; q += 64) {
                unsigned long long comb = (cand[q] << 10) | (unsigned long long)(q + 1);
                if (comb > best) best = comb;
            }
            #pragma unroll
            for (int o = 1; o < 64; o <<= 1) {
                unsigned long long other = __shfl_xor(best, o);
                if (other > best) best = other;
            }
            if (t == 0) {
                int slot = (int)(best & 0x3FFull) - 1;
                unsigned long long key = (best >> 10) - 1ull;   // undo +1
                cand[slot] = 0ull;                              // remove winner
                bcol = 16383 - (int)(key & 0x3FFFull);          // recover column
            }
        }
        __syncthreads();
        acc += x[(size_t)bcol * D_IN + t];                      // coalesced gather (L2/L3)
        __syncthreads();                                        // protect bcol before next pick
    }

    const float aggv  = (m > 0) ? acc * (1.0f / (float)m) : 0.0f;
    const float selfv = x[(size_t)r * D_IN + t];
    unsigned short* hr = h + (size_t)r * (2 * D_IN);
    hr[t]         = f2bfbits(selfv);
    hr[D_IN + t]  = f2bfbits(aggv);
}

// ---------------- kernel W: convert W (f32 [256][512]) → bf16 ----------------
__global__ __launch_bounds__(256) void k_convw(const float* __restrict__ W,
                                               unsigned short* __restrict__ Wb)
{
    int i = (blockIdx.x * 256 + threadIdx.x) * 4;
    float4 v = *(const float4*)(W + i);
    ushort4 u;
    u.x = f2bfbits(v.x); u.y = f2bfbits(v.y); u.z = f2bfbits(v.z); u.w = f2bfbits(v.w);
    *(ushort4*)(Wb + i) = u;
}

// ---------------- kernel 2: out = relu(h @ Wb^T + b), MFMA bf16, f32 out ----------------
// h: [16384][512] bf16. Wb: [256][512] bf16 (B^T form). C[m][n] = sum_k h[m][k]*Wb[n][k].
// Tile BM=128, BN=64, BK=64; 4 waves (2 row x 2 col).
typedef __attribute__((ext_vector_type(8))) short  bf16x8;
typedef __attribute__((ext_vector_type(4))) float  f32x4;
typedef __attribute__((ext_vector_type(4))) int    i32x4;

#define BM 128
#define BN 64
#define BK 64

__global__ __launch_bounds__(256) void k_gemm(
    const unsigned short* __restrict__ h, const unsigned short* __restrict__ Wb,
    const float* __restrict__ bias, float* __restrict__ out)
{
    __shared__ short As[BM * BK];   // rows XOR-swizzled: byte ^= (row&7)<<4
    __shared__ short Bs[BN * BK];

    const int t    = threadIdx.x;
    const int lane = t & 63;
    const int wv   = t >> 6;
    const int wr   = wv >> 1;      // wave row 0..1 (64 rows each)
    const int wc   = wv & 1;       // wave col 0..1 (32 cols each)
    const int m0   = blockIdx.x * BM;
    const int n0   = blockIdx.y * BN;
    const int lr   = lane & 15;    // fragment row/col (A-row, B-col, D-col)
    const int lk   = lane >> 4;    // k-group (8 consecutive k each)

    f32x4 acc[4][2] = {};

    const short* hA = (const short*)h;
    const short* wB = (const short*)Wb;

    for (int k0 = 0; k0 < 2 * D_IN; k0 += BK) {
        // stage A: 128x64 bf16 = 1024 x 16B, 4 chunks/thread
        #pragma unroll
        for (int i = 0; i < 4; ++i) {
            int q = t + i * 256;
            int row = q >> 3, c16 = q & 7;
            i32x4 v = *(const i32x4*)(hA + (size_t)(m0 + row) * 512 + k0 + c16 * 8);
            int ba = (row * 128 + c16 * 16) ^ ((row & 7) << 4);
            *(i32x4*)((char*)As + ba) = v;
        }
        // stage B: 64x64 bf16 = 512 x 16B, 2 chunks/thread
        #pragma unroll
        for (int i = 0; i < 2; ++i) {
            int q = t + i * 256;
            int row = q >> 3, c16 = q & 7;
            i32x4 v = *(const i32x4*)(wB + (size_t)(n0 + row) * 512 + k0 + c16 * 8);
            int ba = (row * 128 + c16 * 16) ^ ((row & 7) << 4);
            *(i32x4*)((char*)Bs + ba) = v;
        }
        __syncthreads();

        #pragma unroll
        for (int kk = 0; kk < BK; kk += 32) {
            bf16x8 af[4], bfr[2];
            #pragma unroll
            for (int mi = 0; mi < 4; ++mi) {
                int row = wr * 64 + mi * 16 + lr;
                int ba = (row * 128 + (kk + lk * 8) * 2) ^ ((row & 7) << 4);
                af[mi] = *(const bf16x8*)((const char*)As + ba);
            }
            #pragma unroll
            for (int ni = 0; ni < 2; ++ni) {
                int row = wc * 32 + ni * 16 + lr;
                int ba = (row * 128 + (kk + lk * 8) * 2) ^ ((row & 7) << 4);
                bfr[ni] = *(const bf16x8*)((const char*)Bs + ba);
            }
            #pragma unroll
            for (int mi = 0; mi < 4; ++mi)
                #pragma unroll
                for (int ni = 0; ni < 2; ++ni)
                    acc[mi][ni] = __builtin_amdgcn_mfma_f32_16x16x32_bf16(
                        af[mi], bfr[ni], acc[mi][ni], 0, 0, 0);
        }
        __syncthreads();
    }

    // epilogue: C/D layout col=lane&15, row=(lane>>4)*4+j  [verified m89]
    #pragma unroll
    for (int mi = 0; mi < 4; ++mi) {
        #pragma unroll
        for (int ni = 0; ni < 2; ++ni) {
            int col = n0 + wc * 32 + ni * 16 + lr;
            float bv = bias[col];
            #pragma unroll
            for (int j = 0; j < 4; ++j) {
                int rowg = m0 + wr * 64 + mi * 16 + lk * 4 + j;
                float v = acc[mi][ni][j] + bv;
                out[(size_t)rowg * D_OUT + col] = v > 0.0f ? v : 0.0f;
            }
        }
    }
}

// ---------------- launch ----------------
extern "C" void kernel_launch(void* const* d_in, const int* in_sizes, int n_in,
                              void* d_out, int out_size, void* d_ws, size_t ws_size,
                              hipStream_t stream) {
    (void)in_sizes; (void)n_in; (void)out_size; (void)ws_size;
    const float* x   = (const float*)d_in[0];
    const float* adj = (const float*)d_in[1];
    const float* W   = (const float*)d_in[2];
    const float* b   = (const float*)d_in[3];

    unsigned short* h  = (unsigned short*)d_ws;                                  // 16.8 MB
    unsigned short* Wb = (unsigned short*)((char*)d_ws + (size_t)N_NODES * 512 * 2);
    float* out = (float*)d_out;

    hipLaunchKernelGGL(k_convw, dim3((D_OUT * 2 * D_IN) / 1024), dim3(256), 0, stream, W, Wb);
    hipLaunchKernelGGL(k_agg,   dim3(N_NODES), dim3(256), 0, stream, x, adj, h);
    hipLaunchKernelGGL(k_gemm,  dim3(N_NODES / BM, D_OUT / BN), dim3(256), 0, stream,
                       h, Wb, b, out);
}

// Round 5
// 241.827 us; speedup vs baseline: 1.9624x; 1.0808x over previous
//
#include <hip/hip_runtime.h>
#include <hip/hip_bf16.h>
#include <stdint.h>

// ---------------- problem constants ----------------
#define N_NODES 16384
#define D_IN    256
#define D_OUT   256
#define K_SAMP  10
#define HALF_FLAT (1u << 27)

// JAX PRNG mode: 1 = jax_threefry_partitionable (verified correct in R3/R4).
#define JAX_PARTITIONABLE 1

__device__ __forceinline__ uint32_t rotl32(uint32_t x, int r) {
    return (x << r) | (x >> (32 - r));
}

// Exact replica of jax threefry2x32 noise bits for flat index i = r*16384 + c, key (0,42).
__device__ __forceinline__ uint32_t jax_noise_bits(uint32_t r, uint32_t c) {
    const uint32_t i  = (r << 14) | c;
    const uint32_t k0 = 0u, k1 = 42u;
    const uint32_t k2 = 42u ^ 0x1BD11BDAu;
    uint32_t x0, x1;
#if JAX_PARTITIONABLE
    x0 = 0u;
    x1 = i;
#else
    const bool lo = (i < HALF_FLAT);
    x0 = lo ? i : (i - HALF_FLAT);
    x1 = lo ? (i + HALF_FLAT) : i;
#endif
    x0 += k0; x1 += k1;
#define TFR4(a,b,cc,d) \
    x0 += x1; x1 = rotl32(x1,a);  x1 ^= x0; \
    x0 += x1; x1 = rotl32(x1,b);  x1 ^= x0; \
    x0 += x1; x1 = rotl32(x1,cc); x1 ^= x0; \
    x0 += x1; x1 = rotl32(x1,d);  x1 ^= x0;
    TFR4(13,15,26,6);   x0 += k1; x1 += k2 + 1u;
    TFR4(17,29,16,24);  x0 += k2; x1 += k0 + 2u;
    TFR4(13,15,26,6);   x0 += k0; x1 += k1 + 3u;
    TFR4(17,29,16,24);  x0 += k1; x1 += k2 + 4u;
    TFR4(13,15,26,6);   x0 += k2; x1 += k0 + 5u;
#undef TFR4
#if JAX_PARTITIONABLE
    return x0 ^ x1;
#else
    return (i < HALF_FLAT) ? x0 : x1;
#endif
}

__device__ __forceinline__ unsigned short f2bfbits(float f) {
    __hip_bfloat16 h = __float2bfloat16(f);
    return *(unsigned short*)&h;
}

// ---------------- kernel 1: wave-per-node sample + aggregate → h=[x|agg] bf16 ------------
// 4 waves/block, each wave owns one node. Stream phase: ballot-compact nonzero COLUMNS
// only (no threefry, no atomics). Then dense threefry (≤2 evals/lane), register-space
// top-10 selection via wave-argmax, coalesced gather, bf16 h-row write.
__global__ __launch_bounds__(256) void k_agg(
    const float* __restrict__ x, const float* __restrict__ adj,
    unsigned short* __restrict__ h)
{
    const int t    = threadIdx.x;
    const int lane = t & 63;
    const int w    = t >> 6;
    const int r    = blockIdx.x * 4 + w;

    __shared__ unsigned short candc[4][128];   // per-wave nonzero-column list

    // ---- stream + compact ----
    const float4* rowp = (const float4*)(adj + (size_t)r * N_NODES);
    int nc = 0;                                 // wave-uniform candidate count
    #pragma unroll 8
    for (int it = 0; it < 64; ++it) {
        float4 v = rowp[it * 64 + lane];
        int cb = (it * 64 + lane) * 4;
        float vv[4] = {v.x, v.y, v.z, v.w};
        #pragma unroll
        for (int j = 0; j < 4; ++j) {
            unsigned long long mask = __ballot(vv[j] != 0.0f);
            if (mask) {
                if (vv[j] != 0.0f) {
                    int below = __builtin_amdgcn_mbcnt_hi(
                        (uint32_t)(mask >> 32),
                        __builtin_amdgcn_mbcnt_lo((uint32_t)mask, 0));
                    int slot = nc + below;
                    if (slot < 128) candc[w][slot] = (unsigned short)(cb + j);
                }
                nc += __popcll(mask);
            }
        }
    }
    __syncthreads();                            // one barrier; makes LDS lists visible
    if (nc > 128) nc = 128;                     // P(deg>128) ~ 0 (17 sigma)

    // ---- dense threefry: keys for candidates lane and lane+64 ----
    unsigned long long k0 = 0ull, k1 = 0ull;
    if (lane < nc) {
        uint32_t c   = candc[w][lane];
        uint32_t u23 = jax_noise_bits((uint32_t)r, c) >> 9;   // monotone with uniform float
        k0 = ((((unsigned long long)u23) << 14) | (unsigned long long)(16383u - c)) + 1ull;
    }
    if (64 + lane < nc) {
        uint32_t c   = candc[w][64 + lane];
        uint32_t u23 = jax_noise_bits((uint32_t)r, c) >> 9;
        k1 = ((((unsigned long long)u23) << 14) | (unsigned long long)(16383u - c)) + 1ull;
    }

    // ---- top-K selection (register space) + gather ----
    const int m = nc < K_SAMP ? nc : K_SAMP;
    float4 acc = {0.f, 0.f, 0.f, 0.f};
    for (int s = 0; s < m; ++s) {
        unsigned long long my = k0 > k1 ? k0 : k1;
        #pragma unroll
        for (int o = 1; o < 64; o <<= 1) {
            unsigned long long other = __shfl_xor(my, o);
            if (other > my) my = other;
        }
        // keys are unique (low 14 bits = distinct column) -> exactly one entry matches
        if (k0 == my) k0 = 0ull; else if (k1 == my) k1 = 0ull;
        const int col = 16383 - (int)((my - 1ull) & 0x3FFFull);
        float4 xv = *(const float4*)(x + (size_t)col * D_IN + lane * 4);
        acc.x += xv.x; acc.y += xv.y; acc.z += xv.z; acc.w += xv.w;
    }
    const float inv = (m > 0) ? 1.0f / (float)m : 0.0f;

    // ---- write h row: [self | agg] bf16 ----
    float4 sv = *(const float4*)(x + (size_t)r * D_IN + lane * 4);
    ushort4 us, ua;
    us.x = f2bfbits(sv.x);        us.y = f2bfbits(sv.y);
    us.z = f2bfbits(sv.z);        us.w = f2bfbits(sv.w);
    ua.x = f2bfbits(acc.x * inv); ua.y = f2bfbits(acc.y * inv);
    ua.z = f2bfbits(acc.z * inv); ua.w = f2bfbits(acc.w * inv);
    unsigned short* hr = h + (size_t)r * (2 * D_IN);
    *(ushort4*)(hr + lane * 4)         = us;
    *(ushort4*)(hr + D_IN + lane * 4)  = ua;
}

// ---------------- kernel W: convert W (f32 [256][512]) → bf16 ----------------
__global__ __launch_bounds__(256) void k_convw(const float* __restrict__ W,
                                               unsigned short* __restrict__ Wb)
{
    int i = (blockIdx.x * 256 + threadIdx.x) * 4;
    float4 v = *(const float4*)(W + i);
    ushort4 u;
    u.x = f2bfbits(v.x); u.y = f2bfbits(v.y); u.z = f2bfbits(v.z); u.w = f2bfbits(v.w);
    *(ushort4*)(Wb + i) = u;
}

// ---------------- kernel 2: out = relu(h @ Wb^T + b), MFMA bf16, f32 out ----------------
// (unchanged from R4 — verified). h:[16384][512] bf16, Wb:[256][512] bf16 (B^T form).
typedef __attribute__((ext_vector_type(8))) short  bf16x8;
typedef __attribute__((ext_vector_type(4))) float  f32x4;
typedef __attribute__((ext_vector_type(4))) int    i32x4;

#define BM 128
#define BN 64
#define BK 64

__global__ __launch_bounds__(256) void k_gemm(
    const unsigned short* __restrict__ h, const unsigned short* __restrict__ Wb,
    const float* __restrict__ bias, float* __restrict__ out)
{
    __shared__ short As[BM * BK];   // rows XOR-swizzled: byte ^= (row&7)<<4
    __shared__ short Bs[BN * BK];

    const int t    = threadIdx.x;
    const int lane = t & 63;
    const int wv   = t >> 6;
    const int wr   = wv >> 1;
    const int wc   = wv & 1;
    const int m0   = blockIdx.x * BM;
    const int n0   = blockIdx.y * BN;
    const int lr   = lane & 15;
    const int lk   = lane >> 4;

    f32x4 acc[4][2] = {};

    const short* hA = (const short*)h;
    const short* wB = (const short*)Wb;

    for (int k0 = 0; k0 < 2 * D_IN; k0 += BK) {
        #pragma unroll
        for (int i = 0; i < 4; ++i) {
            int q = t + i * 256;
            int row = q >> 3, c16 = q & 7;
            i32x4 v = *(const i32x4*)(hA + (size_t)(m0 + row) * 512 + k0 + c16 * 8);
            int ba = (row * 128 + c16 * 16) ^ ((row & 7) << 4);
            *(i32x4*)((char*)As + ba) = v;
        }
        #pragma unroll
        for (int i = 0; i < 2; ++i) {
            int q = t + i * 256;
            int row = q >> 3, c16 = q & 7;
            i32x4 v = *(const i32x4*)(wB + (size_t)(n0 + row) * 512 + k0 + c16 * 8);
            int ba = (row * 128 + c16 * 16) ^ ((row & 7) << 4);
            *(i32x4*)((char*)Bs + ba) = v;
        }
        __syncthreads();

        #pragma unroll
        for (int kk = 0; kk < BK; kk += 32) {
            bf16x8 af[4], bfr[2];
            #pragma unroll
            for (int mi = 0; mi < 4; ++mi) {
                int row = wr * 64 + mi * 16 + lr;
                int ba = (row * 128 + (kk + lk * 8) * 2) ^ ((row & 7) << 4);
                af[mi] = *(const bf16x8*)((const char*)As + ba);
            }
            #pragma unroll
            for (int ni = 0; ni < 2; ++ni) {
                int row = wc * 32 + ni * 16 + lr;
                int ba = (row * 128 + (kk + lk * 8) * 2) ^ ((row & 7) << 4);
                bfr[ni] = *(const bf16x8*)((const char*)Bs + ba);
            }
            #pragma unroll
            for (int mi = 0; mi < 4; ++mi)
                #pragma unroll
                for (int ni = 0; ni < 2; ++ni)
                    acc[mi][ni] = __builtin_amdgcn_mfma_f32_16x16x32_bf16(
                        af[mi], bfr[ni], acc[mi][ni], 0, 0, 0);
        }
        __syncthreads();
    }

    #pragma unroll
    for (int mi = 0; mi < 4; ++mi) {
        #pragma unroll
        for (int ni = 0; ni < 2; ++ni) {
            int col = n0 + wc * 32 + ni * 16 + lr;
            float bv = bias[col];
            #pragma unroll
            for (int j = 0; j < 4; ++j) {
                int rowg = m0 + wr * 64 + mi * 16 + lk * 4 + j;
                float v = acc[mi][ni][j] + bv;
                out[(size_t)rowg * D_OUT + col] = v > 0.0f ? v : 0.0f;
            }
        }
    }
}

// ---------------- launch ----------------
extern "C" void kernel_launch(void* const* d_in, const int* in_sizes, int n_in,
                              void* d_out, int out_size, void* d_ws, size_t ws_size,
                              hipStream_t stream) {
    (void)in_sizes; (void)n_in; (void)out_size; (void)ws_size;
    const float* x   = (const float*)d_in[0];
    const float* adj = (const float*)d_in[1];
    const float* W   = (const float*)d_in[2];
    const float* b   = (const float*)d_in[3];

    unsigned short* hbuf = (unsigned short*)d_ws;                                  // 16.8 MB
    unsigned short* Wb   = (unsigned short*)((char*)d_ws + (size_t)N_NODES * 512 * 2);
    float* out = (float*)d_out;

    hipLaunchKernelGGL(k_convw, dim3((D_OUT * 2 * D_IN) / 1024), dim3(256), 0, stream, W, Wb);
    hipLaunchKernelGGL(k_agg,   dim3(N_NODES / 4), dim3(256), 0, stream, x, adj, hbuf);
    hipLaunchKernelGGL(k_gemm,  dim3(N_NODES / BM, D_OUT / BN), dim3(256), 0, stream,
                       hbuf, Wb, b, out);
}

// Round 6
// 220.027 us; speedup vs baseline: 2.1568x; 1.0991x over previous
//
#include <hip/hip_runtime.h>
#include <hip/hip_bf16.h>
#include <stdint.h>

// ---------------- problem constants ----------------
#define N_NODES 16384
#define D_IN    256
#define D_OUT   256
#define K_SAMP  10
#define HALF_FLAT (1u << 27)

// JAX PRNG mode: 1 = jax_threefry_partitionable (verified correct in R3/R4/R5).
#define JAX_PARTITIONABLE 1

typedef __attribute__((ext_vector_type(4))) float  f32x4;
typedef __attribute__((ext_vector_type(8))) short  bf16x8;
typedef __attribute__((ext_vector_type(4))) int    i32x4;

__device__ __forceinline__ uint32_t rotl32(uint32_t x, int r) {
    return (x << r) | (x >> (32 - r));
}

// Exact replica of jax threefry2x32 noise bits for flat index i = r*16384 + c, key (0,42).
__device__ __forceinline__ uint32_t jax_noise_bits(uint32_t r, uint32_t c) {
    const uint32_t i  = (r << 14) | c;
    const uint32_t k0 = 0u, k1 = 42u;
    const uint32_t k2 = 42u ^ 0x1BD11BDAu;
    uint32_t x0, x1;
#if JAX_PARTITIONABLE
    x0 = 0u;
    x1 = i;
#else
    const bool lo = (i < HALF_FLAT);
    x0 = lo ? i : (i - HALF_FLAT);
    x1 = lo ? (i + HALF_FLAT) : i;
#endif
    x0 += k0; x1 += k1;
#define TFR4(a,b,cc,d) \
    x0 += x1; x1 = rotl32(x1,a);  x1 ^= x0; \
    x0 += x1; x1 = rotl32(x1,b);  x1 ^= x0; \
    x0 += x1; x1 = rotl32(x1,cc); x1 ^= x0; \
    x0 += x1; x1 = rotl32(x1,d);  x1 ^= x0;
    TFR4(13,15,26,6);   x0 += k1; x1 += k2 + 1u;
    TFR4(17,29,16,24);  x0 += k2; x1 += k0 + 2u;
    TFR4(13,15,26,6);   x0 += k0; x1 += k1 + 3u;
    TFR4(17,29,16,24);  x0 += k1; x1 += k2 + 4u;
    TFR4(13,15,26,6);   x0 += k2; x1 += k0 + 5u;
#undef TFR4
#if JAX_PARTITIONABLE
    return x0 ^ x1;
#else
    return (i < HALF_FLAT) ? x0 : x1;
#endif
}

__device__ __forceinline__ unsigned short f2bfbits(float f) {
    __hip_bfloat16 h = __float2bfloat16(f);
    return *(unsigned short*)&h;
}

// ---------------- kernel 1: wave-per-node sample + aggregate → h=[x|agg] bf16 ------------
// 4 waves/block, each wave owns one node. Identical logic to R5 except the adjacency
// stream uses NON-TEMPORAL loads (protect x / h residency in L2/L3 from the 1.07 GB
// stream). Ballot-compact nonzero columns, dense threefry (≤2 evals/lane), register
// top-10 via wave-argmax, coalesced gather, bf16 h-row write.
__global__ __launch_bounds__(256) void k_agg(
    const float* __restrict__ x, const float* __restrict__ adj,
    unsigned short* __restrict__ h)
{
    const int t    = threadIdx.x;
    const int lane = t & 63;
    const int w    = t >> 6;
    const int r    = blockIdx.x * 4 + w;

    __shared__ unsigned short candc[4][128];   // per-wave nonzero-column list

    // ---- stream + compact (non-temporal adjacency reads) ----
    const f32x4* rowp = (const f32x4*)(adj + (size_t)r * N_NODES);
    int nc = 0;                                 // wave-uniform candidate count
    #pragma unroll 8
    for (int it = 0; it < 64; ++it) {
        f32x4 v = __builtin_nontemporal_load(rowp + it * 64 + lane);
        int cb = (it * 64 + lane) * 4;
        #pragma unroll
        for (int j = 0; j < 4; ++j) {
            unsigned long long mask = __ballot(v[j] != 0.0f);
            if (mask) {
                if (v[j] != 0.0f) {
                    int below = __builtin_amdgcn_mbcnt_hi(
                        (uint32_t)(mask >> 32),
                        __builtin_amdgcn_mbcnt_lo((uint32_t)mask, 0));
                    int slot = nc + below;
                    if (slot < 128) candc[w][slot] = (unsigned short)(cb + j);
                }
                nc += __popcll(mask);
            }
        }
    }
    __syncthreads();                            // one barrier; makes LDS lists visible
    if (nc > 128) nc = 128;                     // P(deg>128) ~ 0 (17 sigma)

    // ---- dense threefry: keys for candidates lane and lane+64 ----
    unsigned long long k0 = 0ull, k1 = 0ull;
    if (lane < nc) {
        uint32_t c   = candc[w][lane];
        uint32_t u23 = jax_noise_bits((uint32_t)r, c) >> 9;   // monotone with uniform float
        k0 = ((((unsigned long long)u23) << 14) | (unsigned long long)(16383u - c)) + 1ull;
    }
    if (64 + lane < nc) {
        uint32_t c   = candc[w][64 + lane];
        uint32_t u23 = jax_noise_bits((uint32_t)r, c) >> 9;
        k1 = ((((unsigned long long)u23) << 14) | (unsigned long long)(16383u - c)) + 1ull;
    }

    // ---- top-K selection (register space) + gather ----
    const int m = nc < K_SAMP ? nc : K_SAMP;
    f32x4 acc = {0.f, 0.f, 0.f, 0.f};
    for (int s = 0; s < m; ++s) {
        unsigned long long my = k0 > k1 ? k0 : k1;
        #pragma unroll
        for (int o = 1; o < 64; o <<= 1) {
            unsigned long long other = __shfl_xor(my, o);
            if (other > my) my = other;
        }
        // keys unique (low 14 bits = distinct column) -> exactly one lane/slot matches
        if (k0 == my) k0 = 0ull; else if (k1 == my) k1 = 0ull;
        const int col = 16383 - (int)((my - 1ull) & 0x3FFFull);
        f32x4 xv = *(const f32x4*)(x + (size_t)col * D_IN + lane * 4);
        acc += xv;
    }
    const float inv = (m > 0) ? 1.0f / (float)m : 0.0f;

    // ---- write h row: [self | agg] bf16 ----
    f32x4 sv = *(const f32x4*)(x + (size_t)r * D_IN + lane * 4);
    ushort4 us, ua;
    us.x = f2bfbits(sv[0]);        us.y = f2bfbits(sv[1]);
    us.z = f2bfbits(sv[2]);        us.w = f2bfbits(sv[3]);
    ua.x = f2bfbits(acc[0] * inv); ua.y = f2bfbits(acc[1] * inv);
    ua.z = f2bfbits(acc[2] * inv); ua.w = f2bfbits(acc[3] * inv);
    unsigned short* hr = h + (size_t)r * (2 * D_IN);
    *(ushort4*)(hr + lane * 4)         = us;
    *(ushort4*)(hr + D_IN + lane * 4)  = ua;
}

// ---------------- kernel W: convert W (f32 [256][512]) → bf16 ----------------
__global__ __launch_bounds__(256) void k_convw(const float* __restrict__ W,
                                               unsigned short* __restrict__ Wb)
{
    int i = (blockIdx.x * 256 + threadIdx.x) * 4;
    float4 v = *(const float4*)(W + i);
    ushort4 u;
    u.x = f2bfbits(v.x); u.y = f2bfbits(v.y); u.z = f2bfbits(v.z); u.w = f2bfbits(v.w);
    *(ushort4*)(Wb + i) = u;
}

// ---------------- kernel 2: out = relu(h @ Wb^T + b), MFMA bf16, f32 out ----------------
// v2: BM=64, BN=64, BK=64 → 1024 blocks (4/CU). Double-buffered LDS, single barrier
// per K-step (m97 order: issue loads(t+1) → compute(t) → ds_write(t+1) → barrier).
// Race-check: writes target buf[cur^1] (never concurrently read); read-visibility via
// the end-of-iter barrier (lgkm drained by __syncthreads).
#define BM 64
#define BN 64
#define BK 64

__global__ __launch_bounds__(256) void k_gemm(
    const unsigned short* __restrict__ h, const unsigned short* __restrict__ Wb,
    const float* __restrict__ bias, float* __restrict__ out)
{
    __shared__ short As[2][BM * BK];   // 8KB per buf, rows XOR-swizzled: byte ^= (row&7)<<4
    __shared__ short Bs[2][BN * BK];

    const int t    = threadIdx.x;
    const int lane = t & 63;
    const int wv   = t >> 6;
    const int wr   = wv >> 1;      // wave row 0..1 (32 rows each)
    const int wc   = wv & 1;       // wave col 0..1 (32 cols each)
    const int m0   = blockIdx.x * BM;
    const int n0   = blockIdx.y * BN;
    const int lr   = lane & 15;    // fragment row/col
    const int lk   = lane >> 4;    // k-group (8 consecutive k each)

    f32x4 acc[2][2] = {};

    const short* hA = (const short*)h;
    const short* wB = (const short*)Wb;

    // staging geometry: 512 chunks of 16B per matrix, 2 chunks/thread
    const int q0  = t, q1 = t + 256;
    const int r0  = q0 >> 3, c0 = q0 & 7;
    const int r1  = q1 >> 3, c1 = q1 & 7;
    const int ba0 = (r0 * 128 + c0 * 16) ^ ((r0 & 7) << 4);
    const int ba1 = (r1 * 128 + c1 * 16) ^ ((r1 & 7) << 4);

    // prologue: stage tile 0 into buf 0
    {
        i32x4 a0 = *(const i32x4*)(hA + (size_t)(m0 + r0) * 512 + c0 * 8);
        i32x4 a1 = *(const i32x4*)(hA + (size_t)(m0 + r1) * 512 + c1 * 8);
        i32x4 b0 = *(const i32x4*)(wB + (size_t)(n0 + r0) * 512 + c0 * 8);
        i32x4 b1 = *(const i32x4*)(wB + (size_t)(n0 + r1) * 512 + c1 * 8);
        *(i32x4*)((char*)&As[0][0] + ba0) = a0;
        *(i32x4*)((char*)&As[0][0] + ba1) = a1;
        *(i32x4*)((char*)&Bs[0][0] + ba0) = b0;
        *(i32x4*)((char*)&Bs[0][0] + ba1) = b1;
    }
    __syncthreads();

    for (int tt = 0; tt < 8; ++tt) {
        const int cur = tt & 1;
        i32x4 a0, a1, b0, b1;
        if (tt < 7) {
            const int k0n = (tt + 1) * BK;
            a0 = *(const i32x4*)(hA + (size_t)(m0 + r0) * 512 + k0n + c0 * 8);
            a1 = *(const i32x4*)(hA + (size_t)(m0 + r1) * 512 + k0n + c1 * 8);
            b0 = *(const i32x4*)(wB + (size_t)(n0 + r0) * 512 + k0n + c0 * 8);
            b1 = *(const i32x4*)(wB + (size_t)(n0 + r1) * 512 + k0n + c1 * 8);
        }

        #pragma unroll
        for (int kk = 0; kk < BK; kk += 32) {
            bf16x8 af[2], bf[2];
            #pragma unroll
            for (int mi = 0; mi < 2; ++mi) {
                int row = wr * 32 + mi * 16 + lr;
                int ba = (row * 128 + (kk + lk * 8) * 2) ^ ((row & 7) << 4);
                af[mi] = *(const bf16x8*)((const char*)&As[cur][0] + ba);
            }
            #pragma unroll
            for (int ni = 0; ni < 2; ++ni) {
                int row = wc * 32 + ni * 16 + lr;
                int ba = (row * 128 + (kk + lk * 8) * 2) ^ ((row & 7) << 4);
                bf[ni] = *(const bf16x8*)((const char*)&Bs[cur][0] + ba);
            }
            #pragma unroll
            for (int mi = 0; mi < 2; ++mi)
                #pragma unroll
                for (int ni = 0; ni < 2; ++ni)
                    acc[mi][ni] = __builtin_amdgcn_mfma_f32_16x16x32_bf16(
                        af[mi], bf[ni], acc[mi][ni], 0, 0, 0);
        }

        if (tt < 7) {
            const int nxt = cur ^ 1;
            *(i32x4*)((char*)&As[nxt][0] + ba0) = a0;
            *(i32x4*)((char*)&As[nxt][0] + ba1) = a1;
            *(i32x4*)((char*)&Bs[nxt][0] + ba0) = b0;
            *(i32x4*)((char*)&Bs[nxt][0] + ba1) = b1;
        }
        __syncthreads();
    }

    // epilogue: C/D layout col=lane&15, row=(lane>>4)*4+j  [verified m89]
    #pragma unroll
    for (int mi = 0; mi < 2; ++mi) {
        #pragma unroll
        for (int ni = 0; ni < 2; ++ni) {
            int col = n0 + wc * 32 + ni * 16 + lr;
            float bv = bias[col];
            #pragma unroll
            for (int j = 0; j < 4; ++j) {
                int rowg = m0 + wr * 32 + mi * 16 + lk * 4 + j;
                float v = acc[mi][ni][j] + bv;
                out[(size_t)rowg * D_OUT + col] = v > 0.0f ? v : 0.0f;
            }
        }
    }
}

// ---------------- launch ----------------
extern "C" void kernel_launch(void* const* d_in, const int* in_sizes, int n_in,
                              void* d_out, int out_size, void* d_ws, size_t ws_size,
                              hipStream_t stream) {
    (void)in_sizes; (void)n_in; (void)out_size; (void)ws_size;
    const float* x   = (const float*)d_in[0];
    const float* adj = (const float*)d_in[1];
    const float* W   = (const float*)d_in[2];
    const float* b   = (const float*)d_in[3];

    unsigned short* hbuf = (unsigned short*)d_ws;                                  // 16.8 MB
    unsigned short* Wb   = (unsigned short*)((char*)d_ws + (size_t)N_NODES * 512 * 2);
    float* out = (float*)d_out;

    hipLaunchKernelGGL(k_convw, dim3((D_OUT * 2 * D_IN) / 1024), dim3(256), 0, stream, W, Wb);
    hipLaunchKernelGGL(k_agg,   dim3(N_NODES / 4), dim3(256), 0, stream, x, adj, hbuf);
    hipLaunchKernelGGL(k_gemm,  dim3(N_NODES / BM, D_OUT / BN), dim3(256), 0, stream,
                       hbuf, Wb, b, out);
}